// Round 7
// baseline (177.174 us; speedup 1.0000x reference)
//
#include <hip/hip_runtime.h>
#include <math.h>

// Problem constants (fixed by setup_inputs)
#define N_PTS 16384
#define N_KP  64
#define NF    64
#define KNN   64
#define NWAVE 16   // waves per block

// d_out float offsets: T (2*64*64*16), D (2*64*64), G_kp (2*64*64*4), H_kp (2*64*64*4)
#define OFF_T 0
#define OFF_D 131072
#define OFF_G 139264
#define OFF_H 172032

#define BARRIER_BYTE_OFF 65536   // in d_ws, after the 32 KB rec region
#define NBLOCKS 256u

__device__ __forceinline__ float wsum(float v) {
  #pragma unroll
  for (int m = 1; m < 64; m <<= 1) v += __shfl_xor(v, m, 64);
  return v;
}

// 4x4 SPD inverse via scaled adjugate: A ~ D S D, returns S^{-1} and D=diag(sc).
// One f64 divide + ~40 FMAs (vs Cholesky's ~8 sqrt + ~10 div serial chain).
__device__ __forceinline__ void cof_inv4(const double A[4][4], double Ai[4][4], double sc[4]) {
  #pragma unroll
  for (int c = 0; c < 4; ++c) sc[c] = 1.0/sqrt(fmax(A[c][c], 1e-300));
  double M[4][4];
  #pragma unroll
  for (int r = 0; r < 4; ++r)
    #pragma unroll
    for (int c = 0; c < 4; ++c) M[r][c] = A[r][c]*sc[r]*sc[c];
  const double s0 = M[0][0]*M[1][1] - M[0][1]*M[1][0];
  const double s1 = M[0][0]*M[1][2] - M[0][2]*M[1][0];
  const double s2 = M[0][0]*M[1][3] - M[0][3]*M[1][0];
  const double s3 = M[0][1]*M[1][2] - M[0][2]*M[1][1];
  const double s4 = M[0][1]*M[1][3] - M[0][3]*M[1][1];
  const double s5 = M[0][2]*M[1][3] - M[0][3]*M[1][2];
  const double c5 = M[2][2]*M[3][3] - M[2][3]*M[3][2];
  const double c4 = M[2][1]*M[3][3] - M[2][3]*M[3][1];
  const double c3 = M[2][1]*M[3][2] - M[2][2]*M[3][1];
  const double c2 = M[2][0]*M[3][3] - M[2][3]*M[3][0];
  const double c1 = M[2][0]*M[3][2] - M[2][2]*M[3][0];
  const double c0 = M[2][0]*M[3][1] - M[2][1]*M[3][0];
  const double det = s0*c5 - s1*c4 + s2*c3 + s3*c2 - s4*c1 + s5*c0;
  const double invd = 1.0/fmax(det, 1e-300);   // SPD => det > 0
  Ai[0][0] = ( M[1][1]*c5 - M[1][2]*c4 + M[1][3]*c3)*invd;
  Ai[0][1] = (-M[0][1]*c5 + M[0][2]*c4 - M[0][3]*c3)*invd;
  Ai[0][2] = ( M[3][1]*s5 - M[3][2]*s4 + M[3][3]*s3)*invd;
  Ai[0][3] = (-M[2][1]*s5 + M[2][2]*s4 - M[2][3]*s3)*invd;
  Ai[1][0] = (-M[1][0]*c5 + M[1][2]*c2 - M[1][3]*c1)*invd;
  Ai[1][1] = ( M[0][0]*c5 - M[0][2]*c2 + M[0][3]*c1)*invd;
  Ai[1][2] = (-M[3][0]*s5 + M[3][2]*s2 - M[3][3]*s1)*invd;
  Ai[1][3] = ( M[2][0]*s5 - M[2][2]*s2 + M[2][3]*s1)*invd;
  Ai[2][0] = ( M[1][0]*c4 - M[1][1]*c2 + M[1][3]*c0)*invd;
  Ai[2][1] = (-M[0][0]*c4 + M[0][1]*c2 - M[0][3]*c0)*invd;
  Ai[2][2] = ( M[3][0]*s4 - M[3][1]*s2 + M[3][3]*s0)*invd;
  Ai[2][3] = (-M[2][0]*s4 + M[2][1]*s2 - M[2][3]*s0)*invd;
  Ai[3][0] = (-M[1][0]*c3 + M[1][1]*c1 - M[1][2]*c0)*invd;
  Ai[3][1] = ( M[0][0]*c3 - M[0][1]*c1 + M[0][2]*c0)*invd;
  Ai[3][2] = (-M[3][0]*s3 + M[3][1]*s1 - M[3][2]*s0)*invd;
  Ai[3][3] = ( M[2][0]*s3 - M[2][1]*s1 + M[2][2]*s0)*invd;
}

// Fused kernel. grid (kp=64, b=2, side=2) = 256 blocks, block = 1024 (16 waves).
// 256 blocks x 1024 thr = exactly 1 block/CU => all co-resident => the
// device-scope arrival barrier below cannot deadlock (G16: device-scope
// atomics + fences for cross-XCD visibility).
__global__ __launch_bounds__(1024, 4) void ume_fused(
    const float* __restrict__ sp, const float* __restrict__ sf, const float* __restrict__ skp,
    const float* __restrict__ tp, const float* __restrict__ tf, const float* __restrict__ tkp,
    float* __restrict__ out, double* __restrict__ rec, unsigned int* __restrict__ bar)
{
  const int kp = blockIdx.x, b = blockIdx.y, side = blockIdx.z;
  const int tid  = threadIdx.x;
  const int lane = tid & 63;
  const int w    = tid >> 6;          // wave id 0..15
  const float* pts  = side ? tp  : sp;
  const float* feat = side ? tf  : sf;
  const float* kps  = side ? tkp : skp;

  const float kx = kps[(b*N_KP + kp)*3 + 0];
  const float ky = kps[(b*N_KP + kp)*3 + 1];
  const float kz = kps[(b*N_KP + kp)*3 + 2];

  __shared__ int   s_widx[NWAVE*KNN];
  __shared__ float s_wpx[NWAVE*KNN], s_wpy[NWAVE*KNN], s_wpz[NWAVE*KNN];
  __shared__ int   s_wcount[NWAVE];
  __shared__ int   s_final[KNN];
  __shared__ float s_px[KNN], s_py[KNN], s_pz[KNN];
  __shared__ float s_m0[NWAVE][NF], s_mx[NWAVE][NF], s_my[NWAVE][NF], s_mz[NWAVE][NF];

  // ---- Phase 1 scan: wave w covers [w*1024,(w+1)*1024), 16 chunks preloaded ----
  {
    const float* base = pts + ((size_t)b*N_PTS + w*1024 + lane)*3;
    float px[16], py[16], pz[16];
    #pragma unroll
    for (int k = 0; k < 16; ++k) {
      const float* pp = base + (size_t)k*192;
      px[k] = pp[0]; py[k] = pp[1]; pz[k] = pp[2];
    }
    int running = 0;
    #pragma unroll
    for (int k = 0; k < 16; ++k) {
      const float dx = px[k]-kx, dy = py[k]-ky, dz = pz[k]-kz;
      const bool hit = (dx*dx + dy*dy + dz*dz) < 2.25f;
      const unsigned long long m = __ballot(hit);
      if (hit) {
        const int pos = running + __popcll(m & ((1ull<<lane)-1ull));
        if (pos < KNN) {
          s_widx[w*KNN + pos] = w*1024 + k*64 + lane;
          s_wpx[w*KNN + pos] = px[k]; s_wpy[w*KNN + pos] = py[k]; s_wpz[w*KNN + pos] = pz[k];
        }
      }
      running += (int)__popcll(m);
    }
    if (lane == 0) s_wcount[w] = running > KNN ? KNN : running;
  }
  __syncthreads();

  // ---- redundant per-thread prefix over 16 counts (no extra barrier) ----
  int myoff = 0, total = 0;
  #pragma unroll
  for (int q = 0; q < NWAVE; ++q) {
    const int cq = s_wcount[q];
    if (q < w) myoff += cq;
    total += cq;
  }
  if (total > KNN) total = KNN;

  if (lane < s_wcount[w]) {
    const int slot = myoff + lane;
    if (slot < KNN) {
      s_final[slot] = s_widx[w*KNN + lane];
      s_px[slot] = s_wpx[w*KNN + lane];
      s_py[slot] = s_wpy[w*KNN + lane];
      s_pz[slot] = s_wpz[w*KNN + lane];
    }
  }
  __syncthreads();

  // ---- Moments: 16 groups x 64 features ----
  {
    const int f = lane, g = w;
    float m0 = 0.f, mxv = 0.f, myv = 0.f, mzv = 0.f;
    #pragma unroll
    for (int t = 0; t < 4; ++t) {
      const int k = g + t*NWAVE;
      if (k < total) {
        const float fv = feat[((size_t)b*N_PTS + s_final[k])*NF + f];
        m0  += fv;
        mxv += fv * s_px[k];
        myv += fv * s_py[k];
        mzv += fv * s_pz[k];
      }
    }
    s_m0[g][f] = m0; s_mx[g][f] = mxv; s_my[g][f] = myv; s_mz[g][f] = mzv;
  }
  __syncthreads();

  if (tid < 64) {   // wave 0 finishes phase 1
    float m0 = 0.f, mxv = 0.f, myv = 0.f, mzv = 0.f;
    #pragma unroll
    for (int g = 0; g < NWAVE; ++g) {
      m0  += s_m0[g][lane];
      mxv += s_mx[g][lane];
      myv += s_my[g][lane];
      mzv += s_mz[g][lane];
    }
    const float denom = wsum(m0) + 1e-6f;
    float u[4];
    u[0] = m0/denom; u[1] = mxv/denom; u[2] = myv/denom; u[3] = mzv/denom;

    float* dst = out + (side ? OFF_H : OFF_G) + ((size_t)(b*N_KP+kp)*NF + lane)*4;
    dst[0]=u[0]; dst[1]=u[1]; dst[2]=u[2]; dst[3]=u[3];

    float A[4][4];
    #pragma unroll
    for (int c = 0; c < 4; ++c)
      #pragma unroll
      for (int d = c; d < 4; ++d) {
        const float s = wsum(u[c]*u[d]);
        A[c][d] = s; A[d][c] = s;
      }
    if (lane < 16)
      rec[(size_t)((side*2 + b)*N_KP + kp)*16 + lane] = (double)A[lane>>2][lane&3];
  }

  // ---- device-scope grid barrier (all 256 blocks co-resident) ----
  __threadfence();      // release this thread's global writes device-wide
  __syncthreads();
  if (tid == 0) {
    __hip_atomic_fetch_add(bar, 1u, __ATOMIC_ACQ_REL, __HIP_MEMORY_SCOPE_AGENT);
    while (__hip_atomic_load(bar, __ATOMIC_ACQUIRE, __HIP_MEMORY_SCOPE_AGENT) < NBLOCKS)
      __builtin_amdgcn_s_sleep(2);
  }
  __syncthreads();

  // ---- Phase 2: 32 pairs per block, one per thread (tid < 32) ----
  if (tid >= 32) return;
  const int bid = kp + N_KP*(b + 2*side);        // flat block id 0..255
  const int q   = bid*32 + tid;                  // pair id 0..8191
  const int b2  = q >> 12;
  const int i   = (q >> 6) & 63;
  const int j   = q & 63;

  const float4* Gp = (const float4*)(out + OFF_G) + (size_t)(b2*N_KP + i)*NF;
  const float4* Hp = (const float4*)(out + OFF_H) + (size_t)(b2*N_KP + j)*NF;

  double X[4][4] = {};
  #pragma unroll 4
  for (int f = 0; f < NF; ++f) {
    const float4 g = Gp[f];
    const float4 h = Hp[f];
    const double gc[4] = {(double)g.x, (double)g.y, (double)g.z, (double)g.w};
    const double hc[4] = {(double)h.x, (double)h.y, (double)h.z, (double)h.w};
    #pragma unroll
    for (int c = 0; c < 4; ++c)
      #pragma unroll
      for (int d = 0; d < 4; ++d)
        X[c][d] += hc[c]*gc[d];
  }

  double Ag[4][4], Bh[4][4];
  {
    const double* pg = rec + (size_t)(b2*N_KP + i)*16;        // side 0
    const double* ph = rec + (size_t)((2 + b2)*N_KP + j)*16;  // side 1
    #pragma unroll
    for (int k = 0; k < 16; ++k) { Ag[k>>2][k&3] = pg[k]; Bh[k>>2][k&3] = ph[k]; }
  }
  double Aig[4][4], scg[4], Bih[4][4], sch[4];
  cof_inv4(Ag, Aig, scg);
  cof_inv4(Bh, Bih, sch);

  const double inv_dwl = 1.0/(Ag[0][0] + 2e-16);
  const double wl[3] = {Ag[0][1]*inv_dwl, Ag[0][2]*inv_dwl, Ag[0][3]*inv_dwl};
  const double inv_dmm = 1.0/(X[0][0] + 1e-16);
  const double wr[3] = {X[1][0]*inv_dmm, X[2][0]*inv_dmm, X[3][0]*inv_dmm};

  double M3[3][3];
  #pragma unroll
  for (int r = 0; r < 3; ++r)
    #pragma unroll
    for (int c = 0; c < 3; ++c)
      M3[r][c] = X[1+r][1+c] - wl[c]*X[1+r][0] - wr[r]*X[0][1+c] + wr[r]*wl[c]*X[0][0];

  double C[3][3];
  for (int r = 0; r < 3; ++r)
    for (int c = 0; c < 3; ++c) C[r][c] = M3[c][r];

  double mmax = 0.0;
  for (int r = 0; r < 3; ++r)
    for (int c = 0; c < 3; ++c) mmax = fmax(mmax, fabs(C[r][c]));

  double R[3][3] = {{1,0,0},{0,1,0},{0,0,1}};
  if (mmax > 1e-300) {
    const double is = 1.0/mmax;
    for (int r = 0; r < 3; ++r)
      for (int c = 0; c < 3; ++c) C[r][c] *= is;
    double K[3][3];
    for (int p = 0; p < 3; ++p)
      for (int qq = 0; qq < 3; ++qq) {
        double s = 0.0;
        for (int r = 0; r < 3; ++r) s += C[r][p]*C[r][qq];
        K[p][qq] = s;
      }
    double V[3][3] = {{1,0,0},{0,1,0},{0,0,1}};
    for (int sweep = 0; sweep < 5; ++sweep) {
      for (int p = 0; p < 2; ++p)
        for (int qq = p+1; qq < 3; ++qq) {
          const double apq = K[p][qq];
          if (apq*apq < 1e-26) continue;   // converged (K is O(1)-normalized)
          const double tau = (K[qq][qq] - K[p][p])/(2.0*apq);
          const double t   = (tau >= 0.0 ? 1.0 : -1.0)/(fabs(tau) + sqrt(1.0 + tau*tau));
          const double cth = 1.0/sqrt(1.0 + t*t);
          const double sth = t*cth;
          for (int k = 0; k < 3; ++k) {
            const double a = K[p][k], bb_ = K[qq][k];
            K[p][k] = cth*a - sth*bb_;
            K[qq][k] = sth*a + cth*bb_;
          }
          for (int k = 0; k < 3; ++k) {
            const double a = K[k][p], bb_ = K[k][qq];
            K[k][p] = cth*a - sth*bb_;
            K[k][qq] = sth*a + cth*bb_;
          }
          for (int k = 0; k < 3; ++k) {
            const double a = V[k][p], bb_ = V[k][qq];
            V[k][p] = cth*a - sth*bb_;
            V[k][qq] = sth*a + cth*bb_;
          }
        }
    }
    int o0 = 0, o1 = 1, o2 = 2;
    double e0 = K[0][0], e1 = K[1][1], e2 = K[2][2];
    if (e0 < e1) { double te=e0; e0=e1; e1=te; int to=o0; o0=o1; o1=to; }
    if (e0 < e2) { double te=e0; e0=e2; e2=te; int to=o0; o0=o2; o2=to; }
    if (e1 < e2) { double te=e1; e1=e2; e2=te; int to=o1; o1=o2; o2=to; }
    (void)e0; (void)e1; (void)e2;
    double v1[3] = {V[0][o0], V[1][o0], V[2][o0]};
    double v2[3] = {V[0][o1], V[1][o1], V[2][o1]};
    double u1[3], u2[3];
    for (int r = 0; r < 3; ++r) u1[r] = C[r][0]*v1[0] + C[r][1]*v1[1] + C[r][2]*v1[2];
    const double n1 = sqrt(u1[0]*u1[0] + u1[1]*u1[1] + u1[2]*u1[2]);
    if (n1 > 1e-150) { const double rn = 1.0/n1; u1[0]*=rn; u1[1]*=rn; u1[2]*=rn; }
    else             { u1[0]=1.0; u1[1]=0.0; u1[2]=0.0; }
    for (int r = 0; r < 3; ++r) u2[r] = C[r][0]*v2[0] + C[r][1]*v2[1] + C[r][2]*v2[2];
    const double d12 = u2[0]*u1[0] + u2[1]*u1[1] + u2[2]*u1[2];
    for (int r = 0; r < 3; ++r) u2[r] -= d12*u1[r];
    const double n2 = sqrt(u2[0]*u2[0] + u2[1]*u2[1] + u2[2]*u2[2]);
    if (n2 > 1e-100) { const double rn = 1.0/n2; u2[0]*=rn; u2[1]*=rn; u2[2]*=rn; }
    else {
      double t0, t1, t2;
      if (fabs(u1[0]) < 0.9) { t0=1.0; t1=0.0; t2=0.0; } else { t0=0.0; t1=1.0; t2=0.0; }
      const double dd = t0*u1[0] + t1*u1[1] + t2*u1[2];
      u2[0]=t0-dd*u1[0]; u2[1]=t1-dd*u1[1]; u2[2]=t2-dd*u1[2];
      const double nn = 1.0/sqrt(u2[0]*u2[0] + u2[1]*u2[1] + u2[2]*u2[2]);
      u2[0]*=nn; u2[1]*=nn; u2[2]*=nn;
    }
    const double u3[3] = {u1[1]*u2[2]-u1[2]*u2[1], u1[2]*u2[0]-u1[0]*u2[2], u1[0]*u2[1]-u1[1]*u2[0]};
    const double v3[3] = {v1[1]*v2[2]-v1[2]*v2[1], v1[2]*v2[0]-v1[0]*v2[2], v1[0]*v2[1]-v1[1]*v2[0]};
    for (int r = 0; r < 3; ++r)
      for (int c = 0; c < 3; ++c)
        R[r][c] = u1[r]*v1[c] + u2[r]*v2[c] + u3[r]*v3[c];
  }

  double bb[3];
  for (int d = 0; d < 3; ++d)
    bb[d] = wr[d] - (wl[0]*R[0][d] + wl[1]*R[1][d] + wl[2]*R[2][d]);

  // D = 0.707*sqrt(8 - 2*tr(Bi_hat Xh Ai_hat Xh^T)) on the scaled system
  double Xh[4][4];
  for (int c = 0; c < 4; ++c)
    for (int d = 0; d < 4; ++d) Xh[c][d] = X[c][d]*sch[c]*scg[d];
  double W[4][4];
  for (int r = 0; r < 4; ++r)
    for (int c = 0; c < 4; ++c) {
      double s = 0.0;
      for (int k = 0; k < 4; ++k) s += Bih[r][k]*Xh[k][c];
      W[r][c] = s;
    }
  double tr = 0.0;
  for (int r = 0; r < 4; ++r)
    for (int c = 0; c < 4; ++c) {
      double s = 0.0;
      for (int k = 0; k < 4; ++k) s += W[r][k]*Aig[k][c];
      tr += s*Xh[r][c];
    }
  const double Dv = 0.707*sqrt(fmax(8.0 - 2.0*tr, 0.0));

  float* tptr = out + OFF_T + (size_t)((b2*N_KP + i)*N_KP + j)*16;
  tptr[0]=(float)R[0][0];  tptr[1]=(float)R[1][0];  tptr[2]=(float)R[2][0];  tptr[3]=(float)bb[0];
  tptr[4]=(float)R[0][1];  tptr[5]=(float)R[1][1];  tptr[6]=(float)R[2][1];  tptr[7]=(float)bb[1];
  tptr[8]=(float)R[0][2];  tptr[9]=(float)R[1][2];  tptr[10]=(float)R[2][2]; tptr[11]=(float)bb[2];
  tptr[12]=0.f; tptr[13]=0.f; tptr[14]=0.f; tptr[15]=1.f;

  out[OFF_D + (size_t)(b2*N_KP + i)*N_KP + j] = (float)Dv;
}

extern "C" void kernel_launch(void* const* d_in, const int* in_sizes, int n_in,
                              void* d_out, int out_size, void* d_ws, size_t ws_size,
                              hipStream_t stream) {
  const float* sp  = (const float*)d_in[0];
  const float* sf  = (const float*)d_in[1];
  const float* skp = (const float*)d_in[2];
  const float* tp  = (const float*)d_in[3];
  const float* tf  = (const float*)d_in[4];
  const float* tkp = (const float*)d_in[5];
  float* out = (float*)d_out;
  double* rec = (double*)d_ws;                                    // 32 KB
  unsigned int* bar = (unsigned int*)((char*)d_ws + BARRIER_BYTE_OFF);

  hipMemsetAsync(bar, 0, 64, stream);   // clear barrier counter (d_ws is poisoned)
  dim3 g(N_KP, 2, 2);
  ume_fused<<<g, 1024, 0, stream>>>(sp, sf, skp, tp, tf, tkp, out, rec, bar);
}

// Round 8
// 101.263 us; speedup vs baseline: 1.7496x; 1.7496x over previous
//
#include <hip/hip_runtime.h>
#include <math.h>

// Problem constants (fixed by setup_inputs)
#define N_PTS 16384
#define N_KP  64
#define NF    64
#define KNN   64
#define NWAVE 16   // waves per stage-1 block

// d_out float offsets: T (2*64*64*16), D (2*64*64), G_kp (2*64*64*4), H_kp (2*64*64*4)
#define OFF_T 0
#define OFF_D 131072
#define OFF_G 139264
#define OFF_H 172032

__device__ __forceinline__ float wsum(float v) {
  #pragma unroll
  for (int m = 1; m < 64; m <<= 1) v += __shfl_xor(v, m, 64);
  return v;
}

// Stage 1: parallel ball query + UME moments + per-keypoint Gram records (f64).
// grid (kp=64, b=2, side=2), block = 1024 (16 waves).  [R3 structure - measured best]
__global__ __launch_bounds__(1024) void ume_stage1(
    const float* __restrict__ sp, const float* __restrict__ sf, const float* __restrict__ skp,
    const float* __restrict__ tp, const float* __restrict__ tf, const float* __restrict__ tkp,
    float* __restrict__ out, double* __restrict__ rec)
{
  const int kp = blockIdx.x, b = blockIdx.y, side = blockIdx.z;
  const int tid  = threadIdx.x;
  const int lane = tid & 63;
  const int w    = tid >> 6;          // wave id 0..15
  const float* pts  = side ? tp  : sp;
  const float* feat = side ? tf  : sf;
  const float* kps  = side ? tkp : skp;

  const float kx = kps[(b*N_KP + kp)*3 + 0];
  const float ky = kps[(b*N_KP + kp)*3 + 1];
  const float kz = kps[(b*N_KP + kp)*3 + 2];

  __shared__ int   s_widx[NWAVE*KNN];    // per-wave ordered hit lists (first 64)
  __shared__ int   s_wcount[NWAVE];      // per-wave hit count, capped at 64
  __shared__ int   s_woff[NWAVE];        // exclusive prefix
  __shared__ int   s_total;
  __shared__ int   s_final[KNN];
  __shared__ float s_px[KNN], s_py[KNN], s_pz[KNN];
  __shared__ float s_m0[NWAVE][NF], s_mx[NWAVE][NF], s_my[NWAVE][NF], s_mz[NWAVE][NF];

  // --- Parallel ordered scan: wave w covers points [w*1024, (w+1)*1024) ---
  // Preload all 16 point coords per lane (independent loads -> one latency exposure).
  float px[16], py[16], pz[16];
  const size_t pbase = ((size_t)b*N_PTS + w*1024 + lane)*3;
  #pragma unroll
  for (int k = 0; k < 16; ++k) {
    const float* pp = pts + pbase + (size_t)k*64*3;
    px[k] = pp[0]; py[k] = pp[1]; pz[k] = pp[2];
  }
  int running = 0;
  #pragma unroll
  for (int k = 0; k < 16; ++k) {
    const float dx = px[k]-kx, dy = py[k]-ky, dz = pz[k]-kz;
    const bool hit = (dx*dx + dy*dy + dz*dz) < 2.25f;
    const unsigned long long m = __ballot(hit);
    if (hit) {
      const int pos = running + __popcll(m & ((1ull<<lane)-1ull));
      if (pos < KNN) s_widx[w*KNN + pos] = w*1024 + k*64 + lane;
    }
    running += (int)__popcll(m);
  }
  if (lane == 0) s_wcount[w] = running > KNN ? KNN : running;
  __syncthreads();

  // --- Cross-wave exclusive prefix (16 entries, trivial) ---
  if (tid < NWAVE) {
    int off = 0;
    for (int q = 0; q < tid; ++q) off += s_wcount[q];
    s_woff[tid] = off;
    if (tid == NWAVE-1) {
      int tot = off + s_wcount[tid];
      s_total = tot > KNN ? KNN : tot;
    }
  }
  __syncthreads();

  // --- Parallel compaction into the global first-64 list ---
  {
    const int e = tid & 63, ww = tid >> 6;
    if (e < s_wcount[ww]) {
      const int slot = s_woff[ww] + e;
      if (slot < KNN) s_final[slot] = s_widx[ww*KNN + e];
    }
  }
  __syncthreads();

  const int total = s_total;
  if (tid < KNN && tid < total) {
    const float* pp = pts + ((size_t)b*N_PTS + s_final[tid])*3;
    s_px[tid] = pp[0]; s_py[tid] = pp[1]; s_pz[tid] = pp[2];
  }
  __syncthreads();

  // --- Moments, parallel over 16 groups x 64 features ---
  {
    const int f = tid & 63, g = tid >> 6;
    float m0 = 0.f, mxv = 0.f, myv = 0.f, mzv = 0.f;
    for (int k = g; k < total; k += NWAVE) {
      const float fv = feat[((size_t)b*N_PTS + s_final[k])*NF + f];
      m0  += fv;
      mxv += fv * s_px[k];
      myv += fv * s_py[k];
      mzv += fv * s_pz[k];
    }
    s_m0[g][f] = m0; s_mx[g][f] = mxv; s_my[g][f] = myv; s_mz[g][f] = mzv;
  }
  __syncthreads();

  if (tid >= 64) return;   // wave 0 finishes alone

  float m0 = 0.f, mxv = 0.f, myv = 0.f, mzv = 0.f;
  #pragma unroll
  for (int g = 0; g < NWAVE; ++g) {
    m0  += s_m0[g][lane];
    mxv += s_mx[g][lane];
    myv += s_my[g][lane];
    mzv += s_mz[g][lane];
  }
  const float denom = wsum(m0) + 1e-6f;
  float u[4];
  u[0] = m0/denom; u[1] = mxv/denom; u[2] = myv/denom; u[3] = mzv/denom;

  // um rows ARE the G_kp/H_kp outputs.
  float* dst = out + (side ? OFF_H : OFF_G) + ((size_t)(b*N_KP+kp)*NF + lane)*4;
  dst[0]=u[0]; dst[1]=u[1]; dst[2]=u[2]; dst[3]=u[3];

  // Self-Gram A = U^T U (4x4 symmetric), reduced across the wave (f32 = ref fidelity).
  float A[4][4];
  #pragma unroll
  for (int c = 0; c < 4; ++c)
    #pragma unroll
    for (int d = c; d < 4; ++d) {
      const float s = wsum(u[c]*u[d]);
      A[c][d] = s; A[d][c] = s;
    }

  if (lane == 0) {
    // All lane-0 math in double from the f32 Gram.
    double Ad[4][4];
    for (int c = 0; c < 4; ++c)
      for (int d = 0; d < 4; ++d) Ad[c][d] = (double)A[c][d];
    double sc[4];
    #pragma unroll
    for (int c = 0; c < 4; ++c) sc[c] = 1.0/sqrt(fmax(Ad[c][c], 1e-300));
    double Ah[4][4];
    for (int c = 0; c < 4; ++c)
      for (int d = 0; d < 4; ++d) Ah[c][d] = Ad[c][d]*sc[c]*sc[d];
    // Cholesky Ah = L L^T
    double L[4][4] = {};
    for (int c = 0; c < 4; ++c) {
      double dv = Ah[c][c];
      for (int k = 0; k < c; ++k) dv -= L[c][k]*L[c][k];
      dv = sqrt(fmax(dv, 1e-14));
      L[c][c] = dv;
      for (int r = c+1; r < 4; ++r) {
        double v = Ah[r][c];
        for (int k = 0; k < c; ++k) v -= L[r][k]*L[c][k];
        L[r][c] = v/dv;
      }
    }
    // L^{-1}
    double Li[4][4] = {};
    for (int c = 0; c < 4; ++c) {
      Li[c][c] = 1.0/L[c][c];
      for (int r = c+1; r < 4; ++r) {
        double s = 0.0;
        for (int k = c; k < r; ++k) s += L[r][k]*Li[k][c];
        Li[r][c] = -s/L[r][r];
      }
    }
    // Ah^{-1} = Li^T Li
    double Ai[4][4];
    for (int r = 0; r < 4; ++r)
      for (int c = 0; c < 4; ++c) {
        double s = 0.0;
        for (int k = 0; k < 4; ++k) s += Li[k][r]*Li[k][c];
        Ai[r][c] = s;
      }
    double* rp = rec + (size_t)((side*2 + b)*N_KP + kp)*24;
    for (int k = 0; k < 16; ++k) rp[k] = Ai[k>>2][k&3];
    rp[16]=sc[0]; rp[17]=sc[1]; rp[18]=sc[2]; rp[19]=sc[3];
    const double mg_sq = Ad[0][0] + 1e-16;
    const double dwl = mg_sq + 1e-16;
    rp[20] = Ad[0][1]/dwl;
    rp[21] = Ad[0][2]/dwl;
    rp[22] = Ad[0][3]/dwl;
    rp[23] = 0.0;
  }
}

// Stage 2: per-pair transform + D, all f64. grid (jt=8, it=8, b=2), block=64, one pair/thread.
// R3 structure; serial-chain trims: Jacobi 5 sweeps + convergence skip, reciprocal-multiplies.
__global__ __launch_bounds__(64) void ume_stage2(
    const float* __restrict__ gh, float* __restrict__ out,
    const double* __restrict__ rec)
{
  const int jt = blockIdx.x, it = blockIdx.y, b = blockIdx.z;
  const int lane = threadIdx.x;
  const int i = it*8 + (lane >> 3);
  const int j = jt*8 + (lane & 7);

  const float4* Gp = (const float4*)(gh + OFF_G) + (size_t)(b*N_KP + i)*NF;
  const float4* Hp = (const float4*)(gh + OFF_H) + (size_t)(b*N_KP + j)*NF;

  // Cross-Gram X = H^T G (4x4), accumulated in double.
  double X[4][4] = {};
  for (int f = 0; f < NF; ++f) {
    const float4 g = Gp[f];
    const float4 h = Hp[f];
    const double gc[4] = {(double)g.x, (double)g.y, (double)g.z, (double)g.w};
    const double hc[4] = {(double)h.x, (double)h.y, (double)h.z, (double)h.w};
    #pragma unroll
    for (int c = 0; c < 4; ++c)
      #pragma unroll
      for (int d = 0; d < 4; ++d)
        X[c][d] += hc[c]*gc[d];
  }

  const double* rg = rec + (size_t)(b*N_KP + i)*24;         // G side (side 0)
  const double* rh = rec + (size_t)((2 + b)*N_KP + j)*24;   // H side (side 1)

  const double wl[3] = {rg[20], rg[21], rg[22]};
  const double inv_dmm = 1.0/(X[0][0] + 1e-16);   // mg_mh + EPS_T
  const double wr[3] = {X[1][0]*inv_dmm, X[2][0]*inv_dmm, X[3][0]*inv_dmm};

  // M = right^T left, expanded through the Gram (exact in f64)
  double M[3][3];
  #pragma unroll
  for (int r = 0; r < 3; ++r)
    #pragma unroll
    for (int c = 0; c < 3; ++c)
      M[r][c] = X[1+r][1+c] - wl[c]*X[1+r][0] - wr[r]*X[0][1+c] + wr[r]*wl[c]*X[0][0];

  // C = M^T; R = U diag(1,1,s) V^T of C via eigendecomp of C^T C
  double C[3][3];
  for (int r = 0; r < 3; ++r)
    for (int c = 0; c < 3; ++c) C[r][c] = M[c][r];

  double mmax = 0.0;
  for (int r = 0; r < 3; ++r)
    for (int c = 0; c < 3; ++c) mmax = fmax(mmax, fabs(C[r][c]));

  double R[3][3] = {{1,0,0},{0,1,0},{0,0,1}};
  if (mmax > 1e-300) {
    const double is = 1.0/mmax;
    for (int r = 0; r < 3; ++r)
      for (int c = 0; c < 3; ++c) C[r][c] *= is;
    double K[3][3];
    for (int p = 0; p < 3; ++p)
      for (int q = 0; q < 3; ++q) {
        double s = 0.0;
        for (int r = 0; r < 3; ++r) s += C[r][p]*C[r][q];
        K[p][q] = s;
      }
    double V[3][3] = {{1,0,0},{0,1,0},{0,0,1}};
    for (int sweep = 0; sweep < 5; ++sweep) {
      for (int p = 0; p < 2; ++p)
        for (int q = p+1; q < 3; ++q) {
          const double apq = K[p][q];
          if (apq*apq < 1e-26) continue;   // converged: skip ~800-cycle rotation
          const double tau = (K[q][q] - K[p][p])/(2.0*apq);
          const double t   = (tau >= 0.0 ? 1.0 : -1.0)/(fabs(tau) + sqrt(1.0 + tau*tau));
          const double cth = 1.0/sqrt(1.0 + t*t);
          const double sth = t*cth;
          for (int k = 0; k < 3; ++k) {
            const double a = K[p][k], bb_ = K[q][k];
            K[p][k] = cth*a - sth*bb_;
            K[q][k] = sth*a + cth*bb_;
          }
          for (int k = 0; k < 3; ++k) {
            const double a = K[k][p], bb_ = K[k][q];
            K[k][p] = cth*a - sth*bb_;
            K[k][q] = sth*a + cth*bb_;
          }
          for (int k = 0; k < 3; ++k) {
            const double a = V[k][p], bb_ = V[k][q];
            V[k][p] = cth*a - sth*bb_;
            V[k][q] = sth*a + cth*bb_;
          }
        }
    }
    int o0 = 0, o1 = 1, o2 = 2;
    double e0 = K[0][0], e1 = K[1][1], e2 = K[2][2];
    if (e0 < e1) { double te=e0; e0=e1; e1=te; int to=o0; o0=o1; o1=to; }
    if (e0 < e2) { double te=e0; e0=e2; e2=te; int to=o0; o0=o2; o2=to; }
    if (e1 < e2) { double te=e1; e1=e2; e2=te; int to=o1; o1=o2; o2=to; }
    (void)e0; (void)e1; (void)e2;
    double v1[3] = {V[0][o0], V[1][o0], V[2][o0]};
    double v2[3] = {V[0][o1], V[1][o1], V[2][o1]};
    double u1[3], u2[3];
    for (int r = 0; r < 3; ++r) u1[r] = C[r][0]*v1[0] + C[r][1]*v1[1] + C[r][2]*v1[2];
    const double n1 = sqrt(u1[0]*u1[0] + u1[1]*u1[1] + u1[2]*u1[2]);
    if (n1 > 1e-150) { const double rn = 1.0/n1; u1[0]*=rn; u1[1]*=rn; u1[2]*=rn; }
    else             { u1[0]=1.0; u1[1]=0.0; u1[2]=0.0; }
    for (int r = 0; r < 3; ++r) u2[r] = C[r][0]*v2[0] + C[r][1]*v2[1] + C[r][2]*v2[2];
    const double d12 = u2[0]*u1[0] + u2[1]*u1[1] + u2[2]*u1[2];
    for (int r = 0; r < 3; ++r) u2[r] -= d12*u1[r];
    const double n2 = sqrt(u2[0]*u2[0] + u2[1]*u2[1] + u2[2]*u2[2]);
    if (n2 > 1e-100) { const double rn = 1.0/n2; u2[0]*=rn; u2[1]*=rn; u2[2]*=rn; }
    else {
      double t0, t1, t2;
      if (fabs(u1[0]) < 0.9) { t0=1.0; t1=0.0; t2=0.0; } else { t0=0.0; t1=1.0; t2=0.0; }
      const double dd = t0*u1[0] + t1*u1[1] + t2*u1[2];
      u2[0]=t0-dd*u1[0]; u2[1]=t1-dd*u1[1]; u2[2]=t2-dd*u1[2];
      const double nn = 1.0/sqrt(u2[0]*u2[0] + u2[1]*u2[1] + u2[2]*u2[2]);
      u2[0]*=nn; u2[1]*=nn; u2[2]*=nn;
    }
    const double u3[3] = {u1[1]*u2[2]-u1[2]*u2[1], u1[2]*u2[0]-u1[0]*u2[2], u1[0]*u2[1]-u1[1]*u2[0]};
    const double v3[3] = {v1[1]*v2[2]-v1[2]*v2[1], v1[2]*v2[0]-v1[0]*v2[2], v1[0]*v2[1]-v1[1]*v2[0]};
    for (int r = 0; r < 3; ++r)
      for (int c = 0; c < 3; ++c)
        R[r][c] = u1[r]*v1[c] + u2[r]*v2[c] + u3[r]*v3[c];
  }

  double bb[3];
  for (int d = 0; d < 3; ++d)
    bb[d] = wr[d] - (wl[0]*R[0][d] + wl[1]*R[1][d] + wl[2]*R[2][d]);

  // D = 0.707*sqrt(8 - 2*tr(B^{-1} X A^{-1} X^T)) on the scaled system
  const double sg[4] = {rg[16], rg[17], rg[18], rg[19]};
  const double sh[4] = {rh[16], rh[17], rh[18], rh[19]};
  double Xh[4][4];
  for (int c = 0; c < 4; ++c)
    for (int d = 0; d < 4; ++d) Xh[c][d] = X[c][d]*sh[c]*sg[d];
  double W[4][4];
  for (int r = 0; r < 4; ++r)
    for (int c = 0; c < 4; ++c) {
      double s = 0.0;
      for (int k = 0; k < 4; ++k) s += rh[r*4+k]*Xh[k][c];
      W[r][c] = s;
    }
  double tr = 0.0;
  for (int r = 0; r < 4; ++r)
    for (int c = 0; c < 4; ++c) {
      double s = 0.0;
      for (int k = 0; k < 4; ++k) s += W[r][k]*rg[k*4+c];
      tr += s*Xh[r][c];
    }
  const double Dv = 0.707*sqrt(fmax(8.0 - 2.0*tr, 0.0));

  float* tptr = out + OFF_T + (size_t)((b*N_KP + i)*N_KP + j)*16;
  tptr[0]=(float)R[0][0];  tptr[1]=(float)R[1][0];  tptr[2]=(float)R[2][0];  tptr[3]=(float)bb[0];
  tptr[4]=(float)R[0][1];  tptr[5]=(float)R[1][1];  tptr[6]=(float)R[2][1];  tptr[7]=(float)bb[1];
  tptr[8]=(float)R[0][2];  tptr[9]=(float)R[1][2];  tptr[10]=(float)R[2][2]; tptr[11]=(float)bb[2];
  tptr[12]=0.f; tptr[13]=0.f; tptr[14]=0.f; tptr[15]=1.f;

  out[OFF_D + (size_t)(b*N_KP + i)*N_KP + j] = (float)Dv;
}

extern "C" void kernel_launch(void* const* d_in, const int* in_sizes, int n_in,
                              void* d_out, int out_size, void* d_ws, size_t ws_size,
                              hipStream_t stream) {
  const float* sp  = (const float*)d_in[0];
  const float* sf  = (const float*)d_in[1];
  const float* skp = (const float*)d_in[2];
  const float* tp  = (const float*)d_in[3];
  const float* tf  = (const float*)d_in[4];
  const float* tkp = (const float*)d_in[5];
  float* out = (float*)d_out;
  double* rec = (double*)d_ws;   // 256 * 24 doubles = 48 KB

  dim3 gA(N_KP, 2, 2);
  ume_stage1<<<gA, 1024, 0, stream>>>(sp, sf, skp, tp, tf, tkp, out, rec);
  dim3 gB(8, 8, 2);
  ume_stage2<<<gB, 64, 0, stream>>>(out, out, rec);
}

// Round 9
// 98.022 us; speedup vs baseline: 1.8075x; 1.0331x over previous
//
#include <hip/hip_runtime.h>
#include <math.h>

// Problem constants (fixed by setup_inputs)
#define N_PTS 16384
#define N_KP  64
#define NF    64
#define KNN   64
#define NWAVE 16   // waves per stage-1 block

// d_out float offsets: T (2*64*64*16), D (2*64*64), G_kp (2*64*64*4), H_kp (2*64*64*4)
#define OFF_T 0
#define OFF_D 131072
#define OFF_G 139264
#define OFF_H 172032

__device__ __forceinline__ float wsum(float v) {
  #pragma unroll
  for (int m = 1; m < 64; m <<= 1) v += __shfl_xor(v, m, 64);
  return v;
}

// Stage 1: parallel ball query + UME moments + RAW 4x4 self-Gram record.
// grid (kp=64, b=2, side=2), block = 1024 (16 waves).
// Deliberately small binary: NO f64 math beyond 16 parallel converts/stores.
__global__ __launch_bounds__(1024) void ume_stage1(
    const float* __restrict__ sp, const float* __restrict__ sf, const float* __restrict__ skp,
    const float* __restrict__ tp, const float* __restrict__ tf, const float* __restrict__ tkp,
    float* __restrict__ out, double* __restrict__ rec)
{
  const int kp = blockIdx.x, b = blockIdx.y, side = blockIdx.z;
  const int tid  = threadIdx.x;
  const int lane = tid & 63;
  const int w    = tid >> 6;          // wave id 0..15
  const float* pts  = side ? tp  : sp;
  const float* feat = side ? tf  : sf;
  const float* kps  = side ? tkp : skp;

  const float kx = kps[(b*N_KP + kp)*3 + 0];
  const float ky = kps[(b*N_KP + kp)*3 + 1];
  const float kz = kps[(b*N_KP + kp)*3 + 2];

  __shared__ int   s_widx[NWAVE*KNN];    // per-wave ordered hit lists (first 64)
  __shared__ int   s_wcount[NWAVE];      // per-wave hit count, capped at 64
  __shared__ int   s_woff[NWAVE];        // exclusive prefix
  __shared__ int   s_total;
  __shared__ int   s_final[KNN];
  __shared__ float s_px[KNN], s_py[KNN], s_pz[KNN];
  __shared__ float s_m0[NWAVE][NF], s_mx[NWAVE][NF], s_my[NWAVE][NF], s_mz[NWAVE][NF];

  // --- Parallel ordered scan: wave w covers points [w*1024, (w+1)*1024) ---
  float px[16], py[16], pz[16];
  const size_t pbase = ((size_t)b*N_PTS + w*1024 + lane)*3;
  #pragma unroll
  for (int k = 0; k < 16; ++k) {
    const float* pp = pts + pbase + (size_t)k*64*3;
    px[k] = pp[0]; py[k] = pp[1]; pz[k] = pp[2];
  }
  int running = 0;
  #pragma unroll
  for (int k = 0; k < 16; ++k) {
    const float dx = px[k]-kx, dy = py[k]-ky, dz = pz[k]-kz;
    const bool hit = (dx*dx + dy*dy + dz*dz) < 2.25f;
    const unsigned long long m = __ballot(hit);
    if (hit) {
      const int pos = running + __popcll(m & ((1ull<<lane)-1ull));
      if (pos < KNN) s_widx[w*KNN + pos] = w*1024 + k*64 + lane;
    }
    running += (int)__popcll(m);
  }
  if (lane == 0) s_wcount[w] = running > KNN ? KNN : running;
  __syncthreads();

  // --- Cross-wave exclusive prefix (16 entries, trivial) ---
  if (tid < NWAVE) {
    int off = 0;
    for (int q = 0; q < tid; ++q) off += s_wcount[q];
    s_woff[tid] = off;
    if (tid == NWAVE-1) {
      int tot = off + s_wcount[tid];
      s_total = tot > KNN ? KNN : tot;
    }
  }
  __syncthreads();

  // --- Parallel compaction into the global first-64 list ---
  {
    const int e = tid & 63, ww = tid >> 6;
    if (e < s_wcount[ww]) {
      const int slot = s_woff[ww] + e;
      if (slot < KNN) s_final[slot] = s_widx[ww*KNN + e];
    }
  }
  __syncthreads();

  const int total = s_total;
  if (tid < KNN && tid < total) {
    const float* pp = pts + ((size_t)b*N_PTS + s_final[tid])*3;
    s_px[tid] = pp[0]; s_py[tid] = pp[1]; s_pz[tid] = pp[2];
  }
  __syncthreads();

  // --- Moments, parallel over 16 groups x 64 features ---
  {
    const int f = tid & 63, g = tid >> 6;
    float m0 = 0.f, mxv = 0.f, myv = 0.f, mzv = 0.f;
    for (int k = g; k < total; k += NWAVE) {
      const float fv = feat[((size_t)b*N_PTS + s_final[k])*NF + f];
      m0  += fv;
      mxv += fv * s_px[k];
      myv += fv * s_py[k];
      mzv += fv * s_pz[k];
    }
    s_m0[g][f] = m0; s_mx[g][f] = mxv; s_my[g][f] = myv; s_mz[g][f] = mzv;
  }
  __syncthreads();

  if (tid >= 64) return;   // wave 0 finishes alone

  float m0 = 0.f, mxv = 0.f, myv = 0.f, mzv = 0.f;
  #pragma unroll
  for (int g = 0; g < NWAVE; ++g) {
    m0  += s_m0[g][lane];
    mxv += s_mx[g][lane];
    myv += s_my[g][lane];
    mzv += s_mz[g][lane];
  }
  const float denom = wsum(m0) + 1e-6f;
  float u[4];
  u[0] = m0/denom; u[1] = mxv/denom; u[2] = myv/denom; u[3] = mzv/denom;

  // um rows ARE the G_kp/H_kp outputs.
  float* dst = out + (side ? OFF_H : OFF_G) + ((size_t)(b*N_KP+kp)*NF + lane)*4;
  dst[0]=u[0]; dst[1]=u[1]; dst[2]=u[2]; dst[3]=u[3];

  // Self-Gram A = U^T U (4x4 symmetric), reduced across the wave (f32 = ref fidelity).
  float A[4][4];
  #pragma unroll
  for (int c = 0; c < 4; ++c)
    #pragma unroll
    for (int d = c; d < 4; ++d) {
      const float s = wsum(u[c]*u[d]);
      A[c][d] = s; A[d][c] = s;
    }

  // Record = raw A, 16 doubles, written by 16 lanes in parallel (no serial tail).
  if (lane < 16)
    rec[(size_t)((side*2 + b)*N_KP + kp)*16 + lane] = (double)A[lane>>2][lane&3];
}

// 4x4 SPD inverse via scaled adjugate: A ~ D S D, returns S^{-1} and D=diag(sc).
// One f64 divide + ~40 FMAs (validated in R7).
__device__ __forceinline__ void cof_inv4(const double A[4][4], double Ai[4][4], double sc[4]) {
  #pragma unroll
  for (int c = 0; c < 4; ++c) sc[c] = 1.0/sqrt(fmax(A[c][c], 1e-300));
  double M[4][4];
  #pragma unroll
  for (int r = 0; r < 4; ++r)
    #pragma unroll
    for (int c = 0; c < 4; ++c) M[r][c] = A[r][c]*sc[r]*sc[c];
  const double s0 = M[0][0]*M[1][1] - M[0][1]*M[1][0];
  const double s1 = M[0][0]*M[1][2] - M[0][2]*M[1][0];
  const double s2 = M[0][0]*M[1][3] - M[0][3]*M[1][0];
  const double s3 = M[0][1]*M[1][2] - M[0][2]*M[1][1];
  const double s4 = M[0][1]*M[1][3] - M[0][3]*M[1][1];
  const double s5 = M[0][2]*M[1][3] - M[0][3]*M[1][2];
  const double c5 = M[2][2]*M[3][3] - M[2][3]*M[3][2];
  const double c4 = M[2][1]*M[3][3] - M[2][3]*M[3][1];
  const double c3 = M[2][1]*M[3][2] - M[2][2]*M[3][1];
  const double c2 = M[2][0]*M[3][3] - M[2][3]*M[3][0];
  const double c1 = M[2][0]*M[3][2] - M[2][2]*M[3][0];
  const double c0 = M[2][0]*M[3][1] - M[2][1]*M[3][0];
  const double det = s0*c5 - s1*c4 + s2*c3 + s3*c2 - s4*c1 + s5*c0;
  const double invd = 1.0/fmax(det, 1e-300);   // SPD => det > 0
  Ai[0][0] = ( M[1][1]*c5 - M[1][2]*c4 + M[1][3]*c3)*invd;
  Ai[0][1] = (-M[0][1]*c5 + M[0][2]*c4 - M[0][3]*c3)*invd;
  Ai[0][2] = ( M[3][1]*s5 - M[3][2]*s4 + M[3][3]*s3)*invd;
  Ai[0][3] = (-M[2][1]*s5 + M[2][2]*s4 - M[2][3]*s3)*invd;
  Ai[1][0] = (-M[1][0]*c5 + M[1][2]*c2 - M[1][3]*c1)*invd;
  Ai[1][1] = ( M[0][0]*c5 - M[0][2]*c2 + M[0][3]*c1)*invd;
  Ai[1][2] = (-M[3][0]*s5 + M[3][2]*s2 - M[3][3]*s1)*invd;
  Ai[1][3] = ( M[2][0]*s5 - M[2][2]*s2 + M[2][3]*s1)*invd;
  Ai[2][0] = ( M[1][0]*c4 - M[1][1]*c2 + M[1][3]*c0)*invd;
  Ai[2][1] = (-M[0][0]*c4 + M[0][1]*c2 - M[0][3]*c0)*invd;
  Ai[2][2] = ( M[3][0]*s4 - M[3][1]*s2 + M[3][3]*s0)*invd;
  Ai[2][3] = (-M[2][0]*s4 + M[2][1]*s2 - M[2][3]*s0)*invd;
  Ai[3][0] = (-M[1][0]*c3 + M[1][1]*c1 - M[1][2]*c0)*invd;
  Ai[3][1] = ( M[0][0]*c3 - M[0][1]*c1 + M[0][2]*c0)*invd;
  Ai[3][2] = (-M[3][0]*s3 + M[3][1]*s1 - M[3][2]*s0)*invd;
  Ai[3][3] = ( M[2][0]*s3 - M[2][1]*s1 + M[2][2]*s0)*invd;
}

// Stage 2: per-pair transform + D, all f64. grid = 32 blocks x 256 threads
// (4x fewer CUs fetch this fat binary; same 8192 one-pair threads).
__global__ __launch_bounds__(256) void ume_stage2(
    const float* __restrict__ gh, float* __restrict__ out,
    const double* __restrict__ rec)
{
  const int q  = blockIdx.x*256 + threadIdx.x;   // pair id 0..8191
  const int b2 = q >> 12;
  const int i  = (q >> 6) & 63;
  const int j  = q & 63;

  const float4* Gp = (const float4*)(gh + OFF_G) + (size_t)(b2*N_KP + i)*NF;
  const float4* Hp = (const float4*)(gh + OFF_H) + (size_t)(b2*N_KP + j)*NF;

  // Cross-Gram X = H^T G (4x4), accumulated in double.
  double X[4][4] = {};
  for (int f = 0; f < NF; ++f) {
    const float4 g = Gp[f];
    const float4 h = Hp[f];
    const double gc[4] = {(double)g.x, (double)g.y, (double)g.z, (double)g.w};
    const double hc[4] = {(double)h.x, (double)h.y, (double)h.z, (double)h.w};
    #pragma unroll
    for (int c = 0; c < 4; ++c)
      #pragma unroll
      for (int d = 0; d < 4; ++d)
        X[c][d] += hc[c]*gc[d];
  }

  // Load raw self-Grams and invert locally (validated R5/R7 scheme).
  double Ag[4][4], Bh[4][4];
  {
    const double* pg = rec + (size_t)(b2*N_KP + i)*16;        // side 0 (G)
    const double* ph = rec + (size_t)((2 + b2)*N_KP + j)*16;  // side 1 (H)
    #pragma unroll
    for (int k = 0; k < 16; ++k) { Ag[k>>2][k&3] = pg[k]; Bh[k>>2][k&3] = ph[k]; }
  }
  double Aig[4][4], scg[4], Bih[4][4], sch[4];
  cof_inv4(Ag, Aig, scg);
  cof_inv4(Bh, Bih, sch);

  const double inv_dwl = 1.0/(Ag[0][0] + 2e-16);  // (mg_sq+EPS_T)+EPS_T
  const double wl[3] = {Ag[0][1]*inv_dwl, Ag[0][2]*inv_dwl, Ag[0][3]*inv_dwl};
  const double inv_dmm = 1.0/(X[0][0] + 1e-16);   // mg_mh + EPS_T
  const double wr[3] = {X[1][0]*inv_dmm, X[2][0]*inv_dmm, X[3][0]*inv_dmm};

  // M = right^T left, expanded through the Gram (exact in f64)
  double M3[3][3];
  #pragma unroll
  for (int r = 0; r < 3; ++r)
    #pragma unroll
    for (int c = 0; c < 3; ++c)
      M3[r][c] = X[1+r][1+c] - wl[c]*X[1+r][0] - wr[r]*X[0][1+c] + wr[r]*wl[c]*X[0][0];

  // C = M^T; R = U diag(1,1,s) V^T of C via eigendecomp of C^T C
  double C[3][3];
  for (int r = 0; r < 3; ++r)
    for (int c = 0; c < 3; ++c) C[r][c] = M3[c][r];

  double mmax = 0.0;
  for (int r = 0; r < 3; ++r)
    for (int c = 0; c < 3; ++c) mmax = fmax(mmax, fabs(C[r][c]));

  double R[3][3] = {{1,0,0},{0,1,0},{0,0,1}};
  if (mmax > 1e-300) {
    const double is = 1.0/mmax;
    for (int r = 0; r < 3; ++r)
      for (int c = 0; c < 3; ++c) C[r][c] *= is;
    double K[3][3];
    for (int p = 0; p < 3; ++p)
      for (int qq = 0; qq < 3; ++qq) {
        double s = 0.0;
        for (int r = 0; r < 3; ++r) s += C[r][p]*C[r][qq];
        K[p][qq] = s;
      }
    double V[3][3] = {{1,0,0},{0,1,0},{0,0,1}};
    for (int sweep = 0; sweep < 5; ++sweep) {
      for (int p = 0; p < 2; ++p)
        for (int qq = p+1; qq < 3; ++qq) {
          const double apq = K[p][qq];
          if (apq*apq < 1e-26) continue;   // converged: skip rotation
          const double tau = (K[qq][qq] - K[p][p])/(2.0*apq);
          const double t   = (tau >= 0.0 ? 1.0 : -1.0)/(fabs(tau) + sqrt(1.0 + tau*tau));
          const double cth = 1.0/sqrt(1.0 + t*t);
          const double sth = t*cth;
          for (int k = 0; k < 3; ++k) {
            const double a = K[p][k], bb_ = K[qq][k];
            K[p][k] = cth*a - sth*bb_;
            K[qq][k] = sth*a + cth*bb_;
          }
          for (int k = 0; k < 3; ++k) {
            const double a = K[k][p], bb_ = K[k][qq];
            K[k][p] = cth*a - sth*bb_;
            K[k][qq] = sth*a + cth*bb_;
          }
          for (int k = 0; k < 3; ++k) {
            const double a = V[k][p], bb_ = V[k][qq];
            V[k][p] = cth*a - sth*bb_;
            V[k][qq] = sth*a + cth*bb_;
          }
        }
    }
    int o0 = 0, o1 = 1, o2 = 2;
    double e0 = K[0][0], e1 = K[1][1], e2 = K[2][2];
    if (e0 < e1) { double te=e0; e0=e1; e1=te; int to=o0; o0=o1; o1=to; }
    if (e0 < e2) { double te=e0; e0=e2; e2=te; int to=o0; o0=o2; o2=to; }
    if (e1 < e2) { double te=e1; e1=e2; e2=te; int to=o1; o1=o2; o2=to; }
    (void)e0; (void)e1; (void)e2;
    double v1[3] = {V[0][o0], V[1][o0], V[2][o0]};
    double v2[3] = {V[0][o1], V[1][o1], V[2][o1]};
    double u1[3], u2[3];
    for (int r = 0; r < 3; ++r) u1[r] = C[r][0]*v1[0] + C[r][1]*v1[1] + C[r][2]*v1[2];
    const double n1 = sqrt(u1[0]*u1[0] + u1[1]*u1[1] + u1[2]*u1[2]);
    if (n1 > 1e-150) { const double rn = 1.0/n1; u1[0]*=rn; u1[1]*=rn; u1[2]*=rn; }
    else             { u1[0]=1.0; u1[1]=0.0; u1[2]=0.0; }
    for (int r = 0; r < 3; ++r) u2[r] = C[r][0]*v2[0] + C[r][1]*v2[1] + C[r][2]*v2[2];
    const double d12 = u2[0]*u1[0] + u2[1]*u1[1] + u2[2]*u1[2];
    for (int r = 0; r < 3; ++r) u2[r] -= d12*u1[r];
    const double n2 = sqrt(u2[0]*u2[0] + u2[1]*u2[1] + u2[2]*u2[2]);
    if (n2 > 1e-100) { const double rn = 1.0/n2; u2[0]*=rn; u2[1]*=rn; u2[2]*=rn; }
    else {
      double t0, t1, t2;
      if (fabs(u1[0]) < 0.9) { t0=1.0; t1=0.0; t2=0.0; } else { t0=0.0; t1=1.0; t2=0.0; }
      const double dd = t0*u1[0] + t1*u1[1] + t2*u1[2];
      u2[0]=t0-dd*u1[0]; u2[1]=t1-dd*u1[1]; u2[2]=t2-dd*u1[2];
      const double nn = 1.0/sqrt(u2[0]*u2[0] + u2[1]*u2[1] + u2[2]*u2[2]);
      u2[0]*=nn; u2[1]*=nn; u2[2]*=nn;
    }
    const double u3[3] = {u1[1]*u2[2]-u1[2]*u2[1], u1[2]*u2[0]-u1[0]*u2[2], u1[0]*u2[1]-u1[1]*u2[0]};
    const double v3[3] = {v1[1]*v2[2]-v1[2]*v2[1], v1[2]*v2[0]-v1[0]*v2[2], v1[0]*v2[1]-v1[1]*v2[0]};
    for (int r = 0; r < 3; ++r)
      for (int c = 0; c < 3; ++c)
        R[r][c] = u1[r]*v1[c] + u2[r]*v2[c] + u3[r]*v3[c];
  }

  double bb[3];
  for (int d = 0; d < 3; ++d)
    bb[d] = wr[d] - (wl[0]*R[0][d] + wl[1]*R[1][d] + wl[2]*R[2][d]);

  // D = 0.707*sqrt(8 - 2*tr(Bi_hat Xh Ai_hat Xh^T)) on the scaled system
  double Xh[4][4];
  for (int c = 0; c < 4; ++c)
    for (int d = 0; d < 4; ++d) Xh[c][d] = X[c][d]*sch[c]*scg[d];
  double W[4][4];
  for (int r = 0; r < 4; ++r)
    for (int c = 0; c < 4; ++c) {
      double s = 0.0;
      for (int k = 0; k < 4; ++k) s += Bih[r][k]*Xh[k][c];
      W[r][c] = s;
    }
  double tr = 0.0;
  for (int r = 0; r < 4; ++r)
    for (int c = 0; c < 4; ++c) {
      double s = 0.0;
      for (int k = 0; k < 4; ++k) s += W[r][k]*Aig[k][c];
      tr += s*Xh[r][c];
    }
  const double Dv = 0.707*sqrt(fmax(8.0 - 2.0*tr, 0.0));

  float* tptr = out + OFF_T + (size_t)((b2*N_KP + i)*N_KP + j)*16;
  tptr[0]=(float)R[0][0];  tptr[1]=(float)R[1][0];  tptr[2]=(float)R[2][0];  tptr[3]=(float)bb[0];
  tptr[4]=(float)R[0][1];  tptr[5]=(float)R[1][1];  tptr[6]=(float)R[2][1];  tptr[7]=(float)bb[1];
  tptr[8]=(float)R[0][2];  tptr[9]=(float)R[1][2];  tptr[10]=(float)R[2][2]; tptr[11]=(float)bb[2];
  tptr[12]=0.f; tptr[13]=0.f; tptr[14]=0.f; tptr[15]=1.f;

  out[OFF_D + (size_t)(b2*N_KP + i)*N_KP + j] = (float)Dv;
}

extern "C" void kernel_launch(void* const* d_in, const int* in_sizes, int n_in,
                              void* d_out, int out_size, void* d_ws, size_t ws_size,
                              hipStream_t stream) {
  const float* sp  = (const float*)d_in[0];
  const float* sf  = (const float*)d_in[1];
  const float* skp = (const float*)d_in[2];
  const float* tp  = (const float*)d_in[3];
  const float* tf  = (const float*)d_in[4];
  const float* tkp = (const float*)d_in[5];
  float* out = (float*)d_out;
  double* rec = (double*)d_ws;   // 256 * 16 doubles = 32 KB

  dim3 gA(N_KP, 2, 2);
  ume_stage1<<<gA, 1024, 0, stream>>>(sp, sf, skp, tp, tf, tkp, out, rec);
  ume_stage2<<<32, 256, 0, stream>>>(out, out, rec);
}